// Round 1
// baseline (2520.391 us; speedup 1.0000x reference)
//
#include <hip/hip_runtime.h>

#define T_TOK 8192
#define DIMX 1024
#define HID 4096
#define NE 8
#define TP (T_TOK * 2)   // 16384 routed (token,expert) pairs
#define PADR 256         // pad rows so partial 256-row tiles can over-read safely
#define BK 64

typedef unsigned short ushort_t;
typedef __attribute__((ext_vector_type(4))) float f32x4;
typedef __attribute__((ext_vector_type(8))) short bf16x8;
typedef __attribute__((ext_vector_type(8))) unsigned short u16x8;

__device__ __forceinline__ ushort_t f2bf(float f) {
    unsigned u = __float_as_uint(f);
    u += 0x7FFFu + ((u >> 16) & 1u);   // RNE
    return (ushort_t)(u >> 16);
}
__device__ __forceinline__ float b2f(ushort_t h) {
    return __uint_as_float(((unsigned)h) << 16);
}

// async global->LDS, 16B per lane. LDS dest is wave-uniform base + lane*16.
__device__ __forceinline__ void gload_lds16(const void* g, void* l) {
    __builtin_amdgcn_global_load_lds((const __attribute__((address_space(1))) void*)g,
                                     (__attribute__((address_space(3))) void*)l, 16, 0, 0);
}

__device__ __forceinline__ f32x4 mfma16(bf16x8 a, bf16x8 b, f32x4 c) {
    return __builtin_amdgcn_mfma_f32_16x16x32_bf16(a, b, c, 0, 0, 0);
}

// read one MFMA fragment from a [256][32] bf16 k-slice with chunk-XOR swizzle
__device__ __forceinline__ bf16x8 lds_frag(const ushort_t* sl, int row, int q) {
    return *(const bf16x8*)(sl + row * 32 + (((q) ^ ((row >> 1) & 3)) << 3));
}

// ---------------- routing ----------------

__global__ __launch_bounds__(256) void router_kernel(
    const float* __restrict__ x, const float* __restrict__ rw, const float* __restrict__ rb,
    int* __restrict__ topk_idx, float* __restrict__ topk_w)
{
    __shared__ float s_rw[NE * DIMX];
    int tid = threadIdx.x;
    for (int i = tid * 4; i < NE * DIMX; i += 1024) {
        float4 v = *(const float4*)(rw + i);
        *(float4*)(s_rw + i) = v;
    }
    __syncthreads();
    int lane = tid & 63, wid = tid >> 6;
    int t = blockIdx.x * 4 + wid;
    const float* xr = x + (size_t)t * DIMX;
    float acc[NE];
#pragma unroll
    for (int e = 0; e < NE; e++) acc[e] = 0.f;
    for (int j = 0; j < DIMX; j += 64) {
        float xv = xr[j + lane];
#pragma unroll
        for (int e = 0; e < NE; e++) acc[e] += xv * s_rw[e * DIMX + j + lane];
    }
#pragma unroll
    for (int e = 0; e < NE; e++) {
#pragma unroll
        for (int off = 32; off > 0; off >>= 1) acc[e] += __shfl_xor(acc[e], off, 64);
    }
    if (lane == 0) {
        float v[NE];
#pragma unroll
        for (int e = 0; e < NE; e++) v[e] = acc[e] + rb[e];
        int i0 = 0; float b0 = v[0];
#pragma unroll
        for (int e = 1; e < NE; e++) if (v[e] > b0) { b0 = v[e]; i0 = e; }
        int i1 = -1; float b1v = -1e30f;
#pragma unroll
        for (int e = 0; e < NE; e++) if (e != i0 && v[e] > b1v) { b1v = v[e]; i1 = e; }
        float ex = __expf(b1v - b0);
        float inv = 1.f / (1.f + ex);
        topk_idx[t * 2]     = i0;  topk_idx[t * 2 + 1] = i1;
        topk_w[t * 2]       = inv; topk_w[t * 2 + 1]   = ex * inv;
    }
}

__global__ __launch_bounds__(256) void prefix_kernel(
    const int* __restrict__ topk_idx, int* __restrict__ counts,
    int* __restrict__ offsets, int* __restrict__ cursor)
{
    __shared__ int hist[NE * 256];
    int tid = threadIdx.x;
    int loc[NE];
#pragma unroll
    for (int e = 0; e < NE; e++) loc[e] = 0;
    for (int i = tid; i < TP; i += 256) loc[topk_idx[i]]++;
#pragma unroll
    for (int e = 0; e < NE; e++) hist[e * 256 + tid] = loc[e];
    __syncthreads();
    if (tid < NE) {
        int s = 0;
        for (int j = 0; j < 256; j++) s += hist[tid * 256 + j];
        counts[tid] = s;
        cursor[tid] = 0;
    }
    __syncthreads();
    if (tid == 0) {
        int s = 0;
        for (int e = 0; e < NE; e++) { offsets[e] = s; s += counts[e]; }
    }
}

__global__ __launch_bounds__(256) void sg_kernel(
    const float* __restrict__ x, const int* __restrict__ topk_idx,
    const float* __restrict__ topk_w, const int* __restrict__ offsets,
    int* __restrict__ cursor, ushort_t* __restrict__ Xp,
    float* __restrict__ w_of, int* __restrict__ slot_of)
{
    __shared__ int s_pos[2];
    int t = blockIdx.x;
    if (threadIdx.x == 0) {
        int e0 = topk_idx[2 * t], e1 = topk_idx[2 * t + 1];
        int p0 = offsets[e0] + atomicAdd(&cursor[e0], 1);
        int p1 = offsets[e1] + atomicAdd(&cursor[e1], 1);
        s_pos[0] = p0; s_pos[1] = p1;
        w_of[p0] = topk_w[2 * t]; w_of[p1] = topk_w[2 * t + 1];
        slot_of[2 * t] = p0; slot_of[2 * t + 1] = p1;
    }
    __syncthreads();
    int p0 = s_pos[0], p1 = s_pos[1];
    int i = threadIdx.x;
    float4 v = ((const float4*)(x + (size_t)t * DIMX))[i];
    ushort4 o = make_ushort4(f2bf(v.x), f2bf(v.y), f2bf(v.z), f2bf(v.w));
    ((ushort4*)(Xp + (size_t)p0 * DIMX))[i] = o;
    ((ushort4*)(Xp + (size_t)p1 * DIMX))[i] = o;
}

// ---------------- dtype prep ----------------

__global__ __launch_bounds__(256) void cvt_kernel(
    const float* __restrict__ w1, ushort_t* __restrict__ w1d,
    const float* __restrict__ w2, ushort_t* __restrict__ w2d)
{
    const int n8_w1 = NE * 2 * HID * DIMX / 8;
    const int n8_tot = n8_w1 + NE * DIMX * HID / 8;
    int stride = gridDim.x * 256;
    for (int i = blockIdx.x * 256 + threadIdx.x; i < n8_tot; i += stride) {
        const float* src; ushort_t* dst; int j;
        if (i < n8_w1) { src = w1; dst = w1d; j = i; }
        else           { src = w2; dst = w2d; j = i - n8_w1; }
        float4 a = ((const float4*)src)[j * 2];
        float4 b = ((const float4*)src)[j * 2 + 1];
        u16x8 o = { f2bf(a.x), f2bf(a.y), f2bf(a.z), f2bf(a.w),
                    f2bf(b.x), f2bf(b.y), f2bf(b.z), f2bf(b.w) };
        ((u16x8*)dst)[j] = o;
    }
}

// ---------------- shared 8-phase machinery ----------------
// Tile 256x256, BK=64 as two k-slices of 32. 512 threads = 8 waves (2x4).
// LDS: per operand 2 dbuf x 2 kslice x [256][32] bf16 = 64 KB; total 128 KB.
// Per k-tile: 4 phases, each { ds_read frag subtile; issue one half-slice
// prefetch for kt+1; s_barrier; lgkmcnt(0); setprio(1); 16 MFMA; setprio(0);
// [vmcnt(4) at end of ph1/ph3]; s_barrier }.  vmcnt never drains to 0 in the
// main loop (4 loads always in flight); only the last k-tile waits vmcnt(0).

#define STAGE_A(KS, KN, SN) do { \
    gload_lds16(ag0 + (KN) + (KS) * 32, &As[(SN) * 16384 + (KS) * 8192 + adst0]); \
    gload_lds16(ag1 + (KN) + (KS) * 32, &As[(SN) * 16384 + (KS) * 8192 + adst1]); } while (0)
#define STAGE_B(KS, KN, SN) do { \
    gload_lds16(bg0 + (KN) + (KS) * 32, &Bs[(SN) * 16384 + (KS) * 8192 + adst0]); \
    gload_lds16(bg1 + (KN) + (KS) * 32, &Bs[(SN) * 16384 + (KS) * 8192 + adst1]); } while (0)

#define PH_SYNC_COMPUTE(ACCBASE)                                            \
    asm volatile("s_barrier" ::: "memory");                                 \
    asm volatile("s_waitcnt lgkmcnt(0)" ::: "memory");                      \
    __builtin_amdgcn_s_setprio(1);                                          \
    _Pragma("unroll")                                                       \
    for (int i = 0; i < 4; i++)                                             \
        _Pragma("unroll")                                                   \
        for (int j = 0; j < 4; j++)                                         \
            acc[(ACCBASE) + i][j] = mfma16(af[i], bfr[j], acc[(ACCBASE) + i][j]); \
    __builtin_amdgcn_s_setprio(0);

// ---------------- fc1: H = silu(Xp W1a^T + b1a) * (Xp W1b^T + b1b) ----------------
// B tile interleaves W1a/W1b rows per 16 (tile row r: half=(r>>4)&1,
// hcol = nt*128 + (r>>5)*16 + (r&15)), so gate/value pairs land in the same
// lane as fragments nf and nf+1.
__global__ __launch_bounds__(512, 2) void fc1_kernel(
    const ushort_t* __restrict__ Xp, const ushort_t* __restrict__ w1b,
    const float* __restrict__ b1,
    const int* __restrict__ counts, const int* __restrict__ offsets,
    ushort_t* __restrict__ H, const int nt0)
{
    const int e = blockIdx.z, mt = blockIdx.x, nt = blockIdx.y + nt0;
    const int cnt = counts[e];
    if (mt * 256 >= cnt) return;
    const int base = offsets[e] + mt * 256;
    int rows_valid = cnt - mt * 256; if (rows_valid > 256) rows_valid = 256;

    __shared__ ushort_t As[2 * 2 * 256 * 32];   // 64 KB
    __shared__ ushort_t Bs[2 * 2 * 256 * 32];   // 64 KB

    const int tid = threadIdx.x, lane = tid & 63, wid = tid >> 6;
    const int wave_m = wid >> 2, wave_n = wid & 3;        // 2 x 4 wave grid
    const int wrow0 = wave_m * 128, wcol0 = wave_n * 64;
    const int q = lane >> 4, rA = lane & 15;

    // staging geometry: thread stages rows r0 (i=0) and r0+16 (i=1), chunk cs
    const int r0 = wid * 32 + (lane >> 2);
    const int cs = (lane & 3) ^ ((r0 >> 1) & 3);          // same for r0 and r0+16
    const ushort_t* Ag  = Xp + (size_t)base * DIMX;
    const ushort_t* ag0 = Ag + (size_t)r0 * DIMX + cs * 8;
    const ushort_t* ag1 = Ag + (size_t)(r0 + 16) * DIMX + cs * 8;
    const ushort_t* Bg  = w1b + (size_t)e * 2 * HID * DIMX;
    const int g0 = nt * 128 + wid * 16 + (lane >> 2);     // i=0 -> W1a row, i=1 -> W1b row
    const ushort_t* bg0 = Bg + (size_t)g0 * DIMX + cs * 8;
    const ushort_t* bg1 = Bg + (size_t)(HID + g0) * DIMX + cs * 8;
    const int adst0 = wid * 1024 + lane * 8;              // elements, linear LDS
    const int adst1 = adst0 + 512;

    f32x4 acc[8][4];
#pragma unroll
    for (int mf = 0; mf < 8; mf++)
#pragma unroll
        for (int nf = 0; nf < 4; nf++) acc[mf][nf] = (f32x4){0.f, 0.f, 0.f, 0.f};

    // prologue: stage k-tile 0 into slot 0, order Aks0,Bks0,Aks1,Bks1
    STAGE_A(0, 0, 0); STAGE_B(0, 0, 0); STAGE_A(1, 0, 0); STAGE_B(1, 0, 0);
    asm volatile("s_waitcnt vmcnt(4)" ::: "memory");      // ks0 halves landed
    asm volatile("s_barrier" ::: "memory");

    const int NKT = DIMX / BK;   // 16
#pragma unroll 2
    for (int kt = 0; kt < NKT; ++kt) {
        const int sl = kt & 1, sn = sl ^ 1;
        const ushort_t* A0 = &As[sl * 16384];
        const ushort_t* A1 = A0 + 8192;
        const ushort_t* B0 = &Bs[sl * 16384];
        const ushort_t* B1 = B0 + 8192;
        const bool pf = (kt + 1 < NKT);
        const int kn = (kt + 1) * BK;

        bf16x8 af[4], bfr[4];
        // phase 0: ks0 x m-frags 0..3
#pragma unroll
        for (int j = 0; j < 4; j++) bfr[j] = lds_frag(B0, wcol0 + j * 16 + rA, q);
#pragma unroll
        for (int i = 0; i < 4; i++) af[i] = lds_frag(A0, wrow0 + i * 16 + rA, q);
        if (pf) STAGE_A(0, kn, sn);
        PH_SYNC_COMPUTE(0)
        asm volatile("s_barrier" ::: "memory");

        // phase 1: ks0 x m-frags 4..7
#pragma unroll
        for (int i = 0; i < 4; i++) af[i] = lds_frag(A0, wrow0 + 64 + i * 16 + rA, q);
        if (pf) STAGE_B(0, kn, sn);
        PH_SYNC_COMPUTE(4)
        if (pf) { asm volatile("s_waitcnt vmcnt(4)" ::: "memory"); }
        else    { asm volatile("s_waitcnt vmcnt(0)" ::: "memory"); }
        asm volatile("s_barrier" ::: "memory");

        // phase 2: ks1 x m-frags 0..3
#pragma unroll
        for (int j = 0; j < 4; j++) bfr[j] = lds_frag(B1, wcol0 + j * 16 + rA, q);
#pragma unroll
        for (int i = 0; i < 4; i++) af[i] = lds_frag(A1, wrow0 + i * 16 + rA, q);
        if (pf) STAGE_A(1, kn, sn);
        PH_SYNC_COMPUTE(0)
        asm volatile("s_barrier" ::: "memory");

        // phase 3: ks1 x m-frags 4..7
#pragma unroll
        for (int i = 0; i < 4; i++) af[i] = lds_frag(A1, wrow0 + 64 + i * 16 + rA, q);
        if (pf) STAGE_B(1, kn, sn);
        PH_SYNC_COMPUTE(4)
        if (pf) { asm volatile("s_waitcnt vmcnt(4)" ::: "memory"); }
        else    { asm volatile("s_waitcnt vmcnt(0)" ::: "memory"); }
        asm volatile("s_barrier" ::: "memory");
    }

    // epilogue: frag nf even = gate (W1a), nf odd = value (W1b), same lane.
    const float* b1p = b1 + (size_t)e * 2 * HID;
    const bool full = (rows_valid == 256);
#pragma unroll
    for (int mf = 0; mf < 8; mf++) {
#pragma unroll
        for (int rr = 0; rr < 4; rr++) {
            int row = wrow0 + mf * 16 + q * 4 + rr;
            if (full || row < rows_valid) {
#pragma unroll
                for (int nfp = 0; nfp < 2; nfp++) {
                    int hcol = nt * 128 + (wave_n * 2 + nfp) * 16 + rA;
                    float v1 = acc[mf][2 * nfp][rr] + b1p[hcol];
                    float v2 = acc[mf][2 * nfp + 1][rr] + b1p[HID + hcol];
                    float hv = v1 * v2 / (1.f + __expf(-v1));   // silu(v1)*v2
                    H[(size_t)(base + row) * HID + hcol] = f2bf(hv);
                }
            }
        }
    }
}

// ---------------- fc2: Os[pos] = w_of[pos] * (H[pos] W2^T + b2) ----------------
__global__ __launch_bounds__(512, 2) void fc2_kernel(
    const ushort_t* __restrict__ H, const ushort_t* __restrict__ w2b,
    const float* __restrict__ b2,
    const int* __restrict__ counts, const int* __restrict__ offsets,
    const float* __restrict__ w_of, ushort_t* __restrict__ Os)
{
    const int e = blockIdx.z, mt = blockIdx.x, nt = blockIdx.y;
    const int cnt = counts[e];
    if (mt * 256 >= cnt) return;
    const int base = offsets[e] + mt * 256;
    int rows_valid = cnt - mt * 256; if (rows_valid > 256) rows_valid = 256;

    __shared__ ushort_t As[2 * 2 * 256 * 32];   // 64 KB
    __shared__ ushort_t Bs[2 * 2 * 256 * 32];   // 64 KB

    const int tid = threadIdx.x, lane = tid & 63, wid = tid >> 6;
    const int wave_m = wid >> 2, wave_n = wid & 3;
    const int wrow0 = wave_m * 128, wcol0 = wave_n * 64;
    const int q = lane >> 4, rA = lane & 15;

    const int r0 = wid * 32 + (lane >> 2);
    const int cs = (lane & 3) ^ ((r0 >> 1) & 3);
    const ushort_t* Ag  = H + (size_t)base * HID;
    const ushort_t* ag0 = Ag + (size_t)r0 * HID + cs * 8;
    const ushort_t* ag1 = Ag + (size_t)(r0 + 16) * HID + cs * 8;
    const ushort_t* Bg  = w2b + (size_t)e * DIMX * HID;
    const ushort_t* bg0 = Bg + (size_t)(nt * 256 + r0) * HID + cs * 8;
    const ushort_t* bg1 = Bg + (size_t)(nt * 256 + r0 + 16) * HID + cs * 8;
    const int adst0 = wid * 1024 + lane * 8;
    const int adst1 = adst0 + 512;

    f32x4 acc[8][4];
#pragma unroll
    for (int mf = 0; mf < 8; mf++)
#pragma unroll
        for (int nf = 0; nf < 4; nf++) acc[mf][nf] = (f32x4){0.f, 0.f, 0.f, 0.f};

    STAGE_A(0, 0, 0); STAGE_B(0, 0, 0); STAGE_A(1, 0, 0); STAGE_B(1, 0, 0);
    asm volatile("s_waitcnt vmcnt(4)" ::: "memory");
    asm volatile("s_barrier" ::: "memory");

    const int NKT = HID / BK;   // 64
#pragma unroll 2
    for (int kt = 0; kt < NKT; ++kt) {
        const int sl = kt & 1, sn = sl ^ 1;
        const ushort_t* A0 = &As[sl * 16384];
        const ushort_t* A1 = A0 + 8192;
        const ushort_t* B0 = &Bs[sl * 16384];
        const ushort_t* B1 = B0 + 8192;
        const bool pf = (kt + 1 < NKT);
        const int kn = (kt + 1) * BK;

        bf16x8 af[4], bfr[4];
        // phase 0
#pragma unroll
        for (int j = 0; j < 4; j++) bfr[j] = lds_frag(B0, wcol0 + j * 16 + rA, q);
#pragma unroll
        for (int i = 0; i < 4; i++) af[i] = lds_frag(A0, wrow0 + i * 16 + rA, q);
        if (pf) STAGE_A(0, kn, sn);
        PH_SYNC_COMPUTE(0)
        asm volatile("s_barrier" ::: "memory");

        // phase 1
#pragma unroll
        for (int i = 0; i < 4; i++) af[i] = lds_frag(A0, wrow0 + 64 + i * 16 + rA, q);
        if (pf) STAGE_B(0, kn, sn);
        PH_SYNC_COMPUTE(4)
        if (pf) { asm volatile("s_waitcnt vmcnt(4)" ::: "memory"); }
        else    { asm volatile("s_waitcnt vmcnt(0)" ::: "memory"); }
        asm volatile("s_barrier" ::: "memory");

        // phase 2
#pragma unroll
        for (int j = 0; j < 4; j++) bfr[j] = lds_frag(B1, wcol0 + j * 16 + rA, q);
#pragma unroll
        for (int i = 0; i < 4; i++) af[i] = lds_frag(A1, wrow0 + i * 16 + rA, q);
        if (pf) STAGE_A(1, kn, sn);
        PH_SYNC_COMPUTE(0)
        asm volatile("s_barrier" ::: "memory");

        // phase 3
#pragma unroll
        for (int i = 0; i < 4; i++) af[i] = lds_frag(A1, wrow0 + 64 + i * 16 + rA, q);
        if (pf) STAGE_B(1, kn, sn);
        PH_SYNC_COMPUTE(4)
        if (pf) { asm volatile("s_waitcnt vmcnt(4)" ::: "memory"); }
        else    { asm volatile("s_waitcnt vmcnt(0)" ::: "memory"); }
        asm volatile("s_barrier" ::: "memory");
    }

    const float* b2p = b2 + (size_t)e * DIMX + (size_t)nt * 256;
    const bool full = (rows_valid == 256);
#pragma unroll
    for (int mf = 0; mf < 8; mf++) {
#pragma unroll
        for (int rr = 0; rr < 4; rr++) {
            int row = wrow0 + mf * 16 + q * 4 + rr;
            if (full || row < rows_valid) {
                float wv = w_of[base + row];
#pragma unroll
                for (int nf = 0; nf < 4; nf++) {
                    int col = wcol0 + nf * 16 + rA;
                    float val = (acc[mf][nf][rr] + b2p[col]) * wv;
                    Os[(size_t)(base + row) * DIMX + (size_t)nt * 256 + col] = f2bf(val);
                }
            }
        }
    }
}

// ---------------- combine: out[t] = Os[slot0] + Os[slot1] (already weighted) ----------------
__global__ __launch_bounds__(256) void combine_kernel(
    const ushort_t* __restrict__ Os, const int* __restrict__ slot_of, float* __restrict__ out)
{
    int t = blockIdx.x;
    int p0 = slot_of[t * 2], p1 = slot_of[t * 2 + 1];
    int i = threadIdx.x;
    ushort4 a = ((const ushort4*)(Os + (size_t)p0 * DIMX))[i];
    ushort4 b = ((const ushort4*)(Os + (size_t)p1 * DIMX))[i];
    float4 o;
    o.x = b2f(a.x) + b2f(b.x);
    o.y = b2f(a.y) + b2f(b.y);
    o.z = b2f(a.z) + b2f(b.z);
    o.w = b2f(a.w) + b2f(b.w);
    ((float4*)(out + (size_t)t * DIMX))[i] = o;
}

// ---------------- launch ----------------

extern "C" void kernel_launch(void* const* d_in, const int* in_sizes, int n_in,
                              void* d_out, int out_size, void* d_ws, size_t ws_size,
                              hipStream_t stream) {
    (void)in_sizes; (void)n_in; (void)out_size; (void)ws_size;
    const float* x  = (const float*)d_in[0];
    const float* rw = (const float*)d_in[1];
    const float* rb = (const float*)d_in[2];
    const float* w1 = (const float*)d_in[3];
    const float* b1 = (const float*)d_in[4];
    const float* w2 = (const float*)d_in[5];
    const float* b2 = (const float*)d_in[6];
    float* out = (float*)d_out;

    // workspace layout (~363 MB). Os overlays Xp (dead after fc1).
    char* p = (char*)d_ws;
    ushort_t* w1b = (ushort_t*)p; p += (size_t)NE * 2 * HID * DIMX * 2;        // 128 MB
    ushort_t* w2b = (ushort_t*)p; p += (size_t)NE * DIMX * HID * 2;            //  64 MB
    ushort_t* Xp  = (ushort_t*)p; p += (size_t)(TP + PADR) * DIMX * 2;         //  33 MB
    ushort_t* Hb  = (ushort_t*)p; p += (size_t)(TP + PADR) * HID * 2;          // 136 MB
    int* ints     = (int*)p;      p += 24 * sizeof(int);
    int*   counts  = ints;
    int*   cursor  = ints + 8;
    int*   offsets = ints + 16;
    int*   topk_idx = (int*)p;   p += (size_t)TP * 4;
    float* topk_w   = (float*)p; p += (size_t)TP * 4;
    float* w_of     = (float*)p; p += (size_t)TP * 4;
    int*   slot_of  = (int*)p;   p += (size_t)TP * 4;
    ushort_t* Os = Xp;                  // 32 MB needed, 33.5 MB available

    router_kernel<<<T_TOK / 4, 256, 0, stream>>>(x, rw, rb, topk_idx, topk_w);
    prefix_kernel<<<1, 256, 0, stream>>>(topk_idx, counts, offsets, cursor);
    sg_kernel<<<T_TOK, 256, 0, stream>>>(x, topk_idx, topk_w, offsets, cursor,
                                         Xp, w_of, slot_of);
    cvt_kernel<<<2048, 256, 0, stream>>>(w1, w1b, w2, w2b);

    // fc1: 256x256 tiles over (mt up to 8192 rows, 32 nt of 128 h-cols), two
    // nt-halves for profiler visibility.
    fc1_kernel<<<dim3(32, 16, NE), 512, 0, stream>>>(Xp, w1b, b1, counts, offsets, Hb, 0);
    fc1_kernel<<<dim3(32, 16, NE), 512, 0, stream>>>(Xp, w1b, b1, counts, offsets, Hb, 16);
    // fc2: 256x256 tiles, nt over DIMX/256
    fc2_kernel<<<dim3(32, DIMX / 256, NE), 512, 0, stream>>>(Hb, w2b, b2, counts, offsets, w_of, Os);
    combine_kernel<<<T_TOK, 256, 0, stream>>>(Os, slot_of, out);
}

// Round 2
// 2507.720 us; speedup vs baseline: 1.0051x; 1.0051x over previous
//
#include <hip/hip_runtime.h>

#define T_TOK 8192
#define DIMX 1024
#define HID 4096
#define NE 8
#define TP (T_TOK * 2)   // 16384 routed (token,expert) pairs
#define PADR 256         // pad rows so partial 256-row tiles can over-read safely
#define BK 64

typedef unsigned short ushort_t;
typedef __attribute__((ext_vector_type(4))) float f32x4;
typedef __attribute__((ext_vector_type(8))) short bf16x8;
typedef __attribute__((ext_vector_type(8))) unsigned short u16x8;

__device__ __forceinline__ ushort_t f2bf(float f) {
    unsigned u = __float_as_uint(f);
    u += 0x7FFFu + ((u >> 16) & 1u);   // RNE
    return (ushort_t)(u >> 16);
}
__device__ __forceinline__ float b2f(ushort_t h) {
    return __uint_as_float(((unsigned)h) << 16);
}

// async global->LDS, 16B per lane. LDS dest is wave-uniform base + lane*16.
__device__ __forceinline__ void gload_lds16(const void* g, void* l) {
    __builtin_amdgcn_global_load_lds((const __attribute__((address_space(1))) void*)g,
                                     (__attribute__((address_space(3))) void*)l, 16, 0, 0);
}

__device__ __forceinline__ f32x4 mfma16(bf16x8 a, bf16x8 b, f32x4 c) {
    return __builtin_amdgcn_mfma_f32_16x16x32_bf16(a, b, c, 0, 0, 0);
}

// read one MFMA fragment from a [256][32] bf16 k-slice with chunk-XOR swizzle
__device__ __forceinline__ bf16x8 lds_frag(const ushort_t* sl, int row, int q) {
    return *(const bf16x8*)(sl + row * 32 + (((q) ^ ((row >> 1) & 3)) << 3));
}

// ---------------- routing ----------------

__global__ __launch_bounds__(256) void router_kernel(
    const float* __restrict__ x, const float* __restrict__ rw, const float* __restrict__ rb,
    int* __restrict__ topk_idx, float* __restrict__ topk_w)
{
    __shared__ float s_rw[NE * DIMX];
    int tid = threadIdx.x;
    for (int i = tid * 4; i < NE * DIMX; i += 1024) {
        float4 v = *(const float4*)(rw + i);
        *(float4*)(s_rw + i) = v;
    }
    __syncthreads();
    int lane = tid & 63, wid = tid >> 6;
    int t = blockIdx.x * 4 + wid;
    const float* xr = x + (size_t)t * DIMX;
    float acc[NE];
#pragma unroll
    for (int e = 0; e < NE; e++) acc[e] = 0.f;
    for (int j = 0; j < DIMX; j += 64) {
        float xv = xr[j + lane];
#pragma unroll
        for (int e = 0; e < NE; e++) acc[e] += xv * s_rw[e * DIMX + j + lane];
    }
#pragma unroll
    for (int e = 0; e < NE; e++) {
#pragma unroll
        for (int off = 32; off > 0; off >>= 1) acc[e] += __shfl_xor(acc[e], off, 64);
    }
    if (lane == 0) {
        float v[NE];
#pragma unroll
        for (int e = 0; e < NE; e++) v[e] = acc[e] + rb[e];
        int i0 = 0; float b0 = v[0];
#pragma unroll
        for (int e = 1; e < NE; e++) if (v[e] > b0) { b0 = v[e]; i0 = e; }
        int i1 = -1; float b1v = -1e30f;
#pragma unroll
        for (int e = 0; e < NE; e++) if (e != i0 && v[e] > b1v) { b1v = v[e]; i1 = e; }
        float ex = __expf(b1v - b0);
        float inv = 1.f / (1.f + ex);
        topk_idx[t * 2]     = i0;  topk_idx[t * 2 + 1] = i1;
        topk_w[t * 2]       = inv; topk_w[t * 2 + 1]   = ex * inv;
    }
}

__global__ __launch_bounds__(256) void prefix_kernel(
    const int* __restrict__ topk_idx, int* __restrict__ counts,
    int* __restrict__ offsets, int* __restrict__ cursor)
{
    __shared__ int hist[NE * 256];
    int tid = threadIdx.x;
    int loc[NE];
#pragma unroll
    for (int e = 0; e < NE; e++) loc[e] = 0;
    for (int i = tid; i < TP; i += 256) loc[topk_idx[i]]++;
#pragma unroll
    for (int e = 0; e < NE; e++) hist[e * 256 + tid] = loc[e];
    __syncthreads();
    if (tid < NE) {
        int s = 0;
        for (int j = 0; j < 256; j++) s += hist[tid * 256 + j];
        counts[tid] = s;
        cursor[tid] = 0;
    }
    __syncthreads();
    if (tid == 0) {
        int s = 0;
        for (int e = 0; e < NE; e++) { offsets[e] = s; s += counts[e]; }
    }
}

__global__ __launch_bounds__(256) void sg_kernel(
    const float* __restrict__ x, const int* __restrict__ topk_idx,
    const float* __restrict__ topk_w, const int* __restrict__ offsets,
    int* __restrict__ cursor, ushort_t* __restrict__ Xp,
    float* __restrict__ w_of, int* __restrict__ slot_of)
{
    __shared__ int s_pos[2];
    int t = blockIdx.x;
    if (threadIdx.x == 0) {
        int e0 = topk_idx[2 * t], e1 = topk_idx[2 * t + 1];
        int p0 = offsets[e0] + atomicAdd(&cursor[e0], 1);
        int p1 = offsets[e1] + atomicAdd(&cursor[e1], 1);
        s_pos[0] = p0; s_pos[1] = p1;
        w_of[p0] = topk_w[2 * t]; w_of[p1] = topk_w[2 * t + 1];
        slot_of[2 * t] = p0; slot_of[2 * t + 1] = p1;
    }
    __syncthreads();
    int p0 = s_pos[0], p1 = s_pos[1];
    int i = threadIdx.x;
    float4 v = ((const float4*)(x + (size_t)t * DIMX))[i];
    ushort4 o = make_ushort4(f2bf(v.x), f2bf(v.y), f2bf(v.z), f2bf(v.w));
    ((ushort4*)(Xp + (size_t)p0 * DIMX))[i] = o;
    ((ushort4*)(Xp + (size_t)p1 * DIMX))[i] = o;
}

// ---------------- dtype prep ----------------

__global__ __launch_bounds__(256) void cvt_kernel(
    const float* __restrict__ w1, ushort_t* __restrict__ w1d,
    const float* __restrict__ w2, ushort_t* __restrict__ w2d)
{
    const int n8_w1 = NE * 2 * HID * DIMX / 8;
    const int n8_tot = n8_w1 + NE * DIMX * HID / 8;
    int stride = gridDim.x * 256;
    for (int i = blockIdx.x * 256 + threadIdx.x; i < n8_tot; i += stride) {
        const float* src; ushort_t* dst; int j;
        if (i < n8_w1) { src = w1; dst = w1d; j = i; }
        else           { src = w2; dst = w2d; j = i - n8_w1; }
        float4 a = ((const float4*)src)[j * 2];
        float4 b = ((const float4*)src)[j * 2 + 1];
        u16x8 o = { f2bf(a.x), f2bf(a.y), f2bf(a.z), f2bf(a.w),
                    f2bf(b.x), f2bf(b.y), f2bf(b.z), f2bf(b.w) };
        ((u16x8*)dst)[j] = o;
    }
}

// ---------------- shared 8-phase machinery ----------------
// Tile 256x256, BK=64 as two k-slices of 32. 512 threads = 8 waves (2x4).
// LDS: per operand 2 dbuf x 2 kslice x [256][32] bf16 = 64 KB; total 128 KB.
// Per k-tile: 4 phases, each { ds_read frag subtile; issue one half-slice
// prefetch for kt+1; s_barrier; lgkmcnt(0); setprio(1); 16 MFMA; setprio(0);
// [vmcnt(4) at end of ph1/ph3]; s_barrier }.  vmcnt never drains to 0 in the
// main loop (4 loads always in flight); only the last k-tile waits vmcnt(0).
// HYGIENE (round-2 fix): builtin s_barrier + clobber-less s_waitcnt asm.
// "memory"-clobbered asm is mayLoad/mayStore -> SIInsertWaitcnts flushes
// vmcnt(0)+lgkmcnt(0) before it, destroying the counted-vmcnt pipeline.

#define BARRIER() __builtin_amdgcn_s_barrier()
#define WAIT_VM(N) asm volatile("s_waitcnt vmcnt(" #N ")")
#define WAIT_LGKM0() asm volatile("s_waitcnt lgkmcnt(0)")

#define STAGE_A(KS, KN, SN) do { \
    gload_lds16(ag0 + (KN) + (KS) * 32, &As[(SN) * 16384 + (KS) * 8192 + adst0]); \
    gload_lds16(ag1 + (KN) + (KS) * 32, &As[(SN) * 16384 + (KS) * 8192 + adst1]); } while (0)
#define STAGE_B(KS, KN, SN) do { \
    gload_lds16(bg0 + (KN) + (KS) * 32, &Bs[(SN) * 16384 + (KS) * 8192 + adst0]); \
    gload_lds16(bg1 + (KN) + (KS) * 32, &Bs[(SN) * 16384 + (KS) * 8192 + adst1]); } while (0)

#define PH_SYNC_COMPUTE(ACCBASE)                                            \
    BARRIER();                                                              \
    WAIT_LGKM0();                                                           \
    __builtin_amdgcn_s_setprio(1);                                          \
    _Pragma("unroll")                                                       \
    for (int i = 0; i < 4; i++)                                             \
        _Pragma("unroll")                                                   \
        for (int j = 0; j < 4; j++)                                         \
            acc[(ACCBASE) + i][j] = mfma16(af[i], bfr[j], acc[(ACCBASE) + i][j]); \
    __builtin_amdgcn_s_setprio(0);

// ---------------- fc1: H = silu(Xp W1a^T + b1a) * (Xp W1b^T + b1b) ----------------
// B tile interleaves W1a/W1b rows per 16, so gate/value pairs land in the same
// lane as fragments nf and nf+1.
__global__ __launch_bounds__(512, 2) void fc1_kernel(
    const ushort_t* __restrict__ Xp, const ushort_t* __restrict__ w1b,
    const float* __restrict__ b1,
    const int* __restrict__ counts, const int* __restrict__ offsets,
    ushort_t* __restrict__ H, const int nt0)
{
    const int e = blockIdx.z, mt = blockIdx.x, nt = blockIdx.y + nt0;
    const int cnt = counts[e];
    if (mt * 256 >= cnt) return;
    const int base = offsets[e] + mt * 256;
    int rows_valid = cnt - mt * 256; if (rows_valid > 256) rows_valid = 256;

    __shared__ ushort_t As[2 * 2 * 256 * 32];   // 64 KB
    __shared__ ushort_t Bs[2 * 2 * 256 * 32];   // 64 KB

    const int tid = threadIdx.x, lane = tid & 63, wid = tid >> 6;
    const int wave_m = wid >> 2, wave_n = wid & 3;        // 2 x 4 wave grid
    const int wrow0 = wave_m * 128, wcol0 = wave_n * 64;
    const int q = lane >> 4, rA = lane & 15;

    // staging geometry: thread stages rows r0 (i=0) and r0+16 (i=1), chunk cs
    const int r0 = wid * 32 + (lane >> 2);
    const int cs = (lane & 3) ^ ((r0 >> 1) & 3);          // same for r0 and r0+16
    const ushort_t* Ag  = Xp + (size_t)base * DIMX;
    const ushort_t* ag0 = Ag + (size_t)r0 * DIMX + cs * 8;
    const ushort_t* ag1 = Ag + (size_t)(r0 + 16) * DIMX + cs * 8;
    const ushort_t* Bg  = w1b + (size_t)e * 2 * HID * DIMX;
    const int g0 = nt * 128 + wid * 16 + (lane >> 2);     // i=0 -> W1a row, i=1 -> W1b row
    const ushort_t* bg0 = Bg + (size_t)g0 * DIMX + cs * 8;
    const ushort_t* bg1 = Bg + (size_t)(HID + g0) * DIMX + cs * 8;
    const int adst0 = wid * 1024 + lane * 8;              // elements, linear LDS
    const int adst1 = adst0 + 512;

    f32x4 acc[8][4];
#pragma unroll
    for (int mf = 0; mf < 8; mf++)
#pragma unroll
        for (int nf = 0; nf < 4; nf++) acc[mf][nf] = (f32x4){0.f, 0.f, 0.f, 0.f};

    // prologue: stage k-tile 0 into slot 0, order Aks0,Bks0,Aks1,Bks1
    STAGE_A(0, 0, 0); STAGE_B(0, 0, 0); STAGE_A(1, 0, 0); STAGE_B(1, 0, 0);
    WAIT_VM(4);      // ks0 halves landed
    BARRIER();

    const int NKT = DIMX / BK;   // 16
#pragma unroll 2
    for (int kt = 0; kt < NKT; ++kt) {
        const int sl = kt & 1, sn = sl ^ 1;
        const ushort_t* A0 = &As[sl * 16384];
        const ushort_t* A1 = A0 + 8192;
        const ushort_t* B0 = &Bs[sl * 16384];
        const ushort_t* B1 = B0 + 8192;
        const bool pf = (kt + 1 < NKT);
        const int kn = (kt + 1) * BK;

        bf16x8 af[4], bfr[4];
        // phase 0: ks0 x m-frags 0..3
#pragma unroll
        for (int j = 0; j < 4; j++) bfr[j] = lds_frag(B0, wcol0 + j * 16 + rA, q);
#pragma unroll
        for (int i = 0; i < 4; i++) af[i] = lds_frag(A0, wrow0 + i * 16 + rA, q);
        if (pf) STAGE_A(0, kn, sn);
        PH_SYNC_COMPUTE(0)
        BARRIER();

        // phase 1: ks0 x m-frags 4..7
#pragma unroll
        for (int i = 0; i < 4; i++) af[i] = lds_frag(A0, wrow0 + 64 + i * 16 + rA, q);
        if (pf) STAGE_B(0, kn, sn);
        PH_SYNC_COMPUTE(4)
        if (pf) { WAIT_VM(4); } else { WAIT_VM(0); }
        BARRIER();

        // phase 2: ks1 x m-frags 0..3
#pragma unroll
        for (int j = 0; j < 4; j++) bfr[j] = lds_frag(B1, wcol0 + j * 16 + rA, q);
#pragma unroll
        for (int i = 0; i < 4; i++) af[i] = lds_frag(A1, wrow0 + i * 16 + rA, q);
        if (pf) STAGE_A(1, kn, sn);
        PH_SYNC_COMPUTE(0)
        BARRIER();

        // phase 3: ks1 x m-frags 4..7
#pragma unroll
        for (int i = 0; i < 4; i++) af[i] = lds_frag(A1, wrow0 + 64 + i * 16 + rA, q);
        if (pf) STAGE_B(1, kn, sn);
        PH_SYNC_COMPUTE(4)
        if (pf) { WAIT_VM(4); } else { WAIT_VM(0); }
        BARRIER();
    }

    // epilogue: frag nf even = gate (W1a), nf odd = value (W1b), same lane.
    const float* b1p = b1 + (size_t)e * 2 * HID;
    const bool full = (rows_valid == 256);
#pragma unroll
    for (int mf = 0; mf < 8; mf++) {
#pragma unroll
        for (int rr = 0; rr < 4; rr++) {
            int row = wrow0 + mf * 16 + q * 4 + rr;
            if (full || row < rows_valid) {
#pragma unroll
                for (int nfp = 0; nfp < 2; nfp++) {
                    int hcol = nt * 128 + (wave_n * 2 + nfp) * 16 + rA;
                    float v1 = acc[mf][2 * nfp][rr] + b1p[hcol];
                    float v2 = acc[mf][2 * nfp + 1][rr] + b1p[HID + hcol];
                    float hv = v1 * v2 / (1.f + __expf(-v1));   // silu(v1)*v2
                    H[(size_t)(base + row) * HID + hcol] = f2bf(hv);
                }
            }
        }
    }
}

// ---------------- fc2: Os[pos] = w_of[pos] * (H[pos] W2^T + b2) ----------------
__global__ __launch_bounds__(512, 2) void fc2_kernel(
    const ushort_t* __restrict__ H, const ushort_t* __restrict__ w2b,
    const float* __restrict__ b2,
    const int* __restrict__ counts, const int* __restrict__ offsets,
    const float* __restrict__ w_of, ushort_t* __restrict__ Os)
{
    const int e = blockIdx.z, mt = blockIdx.x, nt = blockIdx.y;
    const int cnt = counts[e];
    if (mt * 256 >= cnt) return;
    const int base = offsets[e] + mt * 256;
    int rows_valid = cnt - mt * 256; if (rows_valid > 256) rows_valid = 256;

    __shared__ ushort_t As[2 * 2 * 256 * 32];   // 64 KB
    __shared__ ushort_t Bs[2 * 2 * 256 * 32];   // 64 KB

    const int tid = threadIdx.x, lane = tid & 63, wid = tid >> 6;
    const int wave_m = wid >> 2, wave_n = wid & 3;
    const int wrow0 = wave_m * 128, wcol0 = wave_n * 64;
    const int q = lane >> 4, rA = lane & 15;

    const int r0 = wid * 32 + (lane >> 2);
    const int cs = (lane & 3) ^ ((r0 >> 1) & 3);
    const ushort_t* Ag  = H + (size_t)base * HID;
    const ushort_t* ag0 = Ag + (size_t)r0 * HID + cs * 8;
    const ushort_t* ag1 = Ag + (size_t)(r0 + 16) * HID + cs * 8;
    const ushort_t* Bg  = w2b + (size_t)e * DIMX * HID;
    const ushort_t* bg0 = Bg + (size_t)(nt * 256 + r0) * HID + cs * 8;
    const ushort_t* bg1 = Bg + (size_t)(nt * 256 + r0 + 16) * HID + cs * 8;
    const int adst0 = wid * 1024 + lane * 8;
    const int adst1 = adst0 + 512;

    f32x4 acc[8][4];
#pragma unroll
    for (int mf = 0; mf < 8; mf++)
#pragma unroll
        for (int nf = 0; nf < 4; nf++) acc[mf][nf] = (f32x4){0.f, 0.f, 0.f, 0.f};

    STAGE_A(0, 0, 0); STAGE_B(0, 0, 0); STAGE_A(1, 0, 0); STAGE_B(1, 0, 0);
    WAIT_VM(4);
    BARRIER();

    const int NKT = HID / BK;   // 64
#pragma unroll 2
    for (int kt = 0; kt < NKT; ++kt) {
        const int sl = kt & 1, sn = sl ^ 1;
        const ushort_t* A0 = &As[sl * 16384];
        const ushort_t* A1 = A0 + 8192;
        const ushort_t* B0 = &Bs[sl * 16384];
        const ushort_t* B1 = B0 + 8192;
        const bool pf = (kt + 1 < NKT);
        const int kn = (kt + 1) * BK;

        bf16x8 af[4], bfr[4];
        // phase 0
#pragma unroll
        for (int j = 0; j < 4; j++) bfr[j] = lds_frag(B0, wcol0 + j * 16 + rA, q);
#pragma unroll
        for (int i = 0; i < 4; i++) af[i] = lds_frag(A0, wrow0 + i * 16 + rA, q);
        if (pf) STAGE_A(0, kn, sn);
        PH_SYNC_COMPUTE(0)
        BARRIER();

        // phase 1
#pragma unroll
        for (int i = 0; i < 4; i++) af[i] = lds_frag(A0, wrow0 + 64 + i * 16 + rA, q);
        if (pf) STAGE_B(0, kn, sn);
        PH_SYNC_COMPUTE(4)
        if (pf) { WAIT_VM(4); } else { WAIT_VM(0); }
        BARRIER();

        // phase 2
#pragma unroll
        for (int j = 0; j < 4; j++) bfr[j] = lds_frag(B1, wcol0 + j * 16 + rA, q);
#pragma unroll
        for (int i = 0; i < 4; i++) af[i] = lds_frag(A1, wrow0 + i * 16 + rA, q);
        if (pf) STAGE_A(1, kn, sn);
        PH_SYNC_COMPUTE(0)
        BARRIER();

        // phase 3
#pragma unroll
        for (int i = 0; i < 4; i++) af[i] = lds_frag(A1, wrow0 + 64 + i * 16 + rA, q);
        if (pf) STAGE_B(1, kn, sn);
        PH_SYNC_COMPUTE(4)
        if (pf) { WAIT_VM(4); } else { WAIT_VM(0); }
        BARRIER();
    }

    const float* b2p = b2 + (size_t)e * DIMX + (size_t)nt * 256;
    const bool full = (rows_valid == 256);
#pragma unroll
    for (int mf = 0; mf < 8; mf++) {
#pragma unroll
        for (int rr = 0; rr < 4; rr++) {
            int row = wrow0 + mf * 16 + q * 4 + rr;
            if (full || row < rows_valid) {
                float wv = w_of[base + row];
#pragma unroll
                for (int nf = 0; nf < 4; nf++) {
                    int col = wcol0 + nf * 16 + rA;
                    float val = (acc[mf][nf][rr] + b2p[col]) * wv;
                    Os[(size_t)(base + row) * DIMX + (size_t)nt * 256 + col] = f2bf(val);
                }
            }
        }
    }
}

// ---------------- combine: out[t] = Os[slot0] + Os[slot1] (already weighted) ----------------
__global__ __launch_bounds__(256) void combine_kernel(
    const ushort_t* __restrict__ Os, const int* __restrict__ slot_of, float* __restrict__ out)
{
    int t = blockIdx.x;
    int p0 = slot_of[t * 2], p1 = slot_of[t * 2 + 1];
    int i = threadIdx.x;
    ushort4 a = ((const ushort4*)(Os + (size_t)p0 * DIMX))[i];
    ushort4 b = ((const ushort4*)(Os + (size_t)p1 * DIMX))[i];
    float4 o;
    o.x = b2f(a.x) + b2f(b.x);
    o.y = b2f(a.y) + b2f(b.y);
    o.z = b2f(a.z) + b2f(b.z);
    o.w = b2f(a.w) + b2f(b.w);
    ((float4*)(out + (size_t)t * DIMX))[i] = o;
}

// ---------------- launch ----------------

extern "C" void kernel_launch(void* const* d_in, const int* in_sizes, int n_in,
                              void* d_out, int out_size, void* d_ws, size_t ws_size,
                              hipStream_t stream) {
    (void)in_sizes; (void)n_in; (void)out_size; (void)ws_size;
    const float* x  = (const float*)d_in[0];
    const float* rw = (const float*)d_in[1];
    const float* rb = (const float*)d_in[2];
    const float* w1 = (const float*)d_in[3];
    const float* b1 = (const float*)d_in[4];
    const float* w2 = (const float*)d_in[5];
    const float* b2 = (const float*)d_in[6];
    float* out = (float*)d_out;

    // workspace layout (~363 MB). Os overlays Xp (dead after fc1).
    char* p = (char*)d_ws;
    ushort_t* w1b = (ushort_t*)p; p += (size_t)NE * 2 * HID * DIMX * 2;        // 128 MB
    ushort_t* w2b = (ushort_t*)p; p += (size_t)NE * DIMX * HID * 2;            //  64 MB
    ushort_t* Xp  = (ushort_t*)p; p += (size_t)(TP + PADR) * DIMX * 2;         //  33 MB
    ushort_t* Hb  = (ushort_t*)p; p += (size_t)(TP + PADR) * HID * 2;          // 136 MB
    int* ints     = (int*)p;      p += 24 * sizeof(int);
    int*   counts  = ints;
    int*   cursor  = ints + 8;
    int*   offsets = ints + 16;
    int*   topk_idx = (int*)p;   p += (size_t)TP * 4;
    float* topk_w   = (float*)p; p += (size_t)TP * 4;
    float* w_of     = (float*)p; p += (size_t)TP * 4;
    int*   slot_of  = (int*)p;   p += (size_t)TP * 4;
    ushort_t* Os = Xp;                  // 32 MB needed, 33.5 MB available

    router_kernel<<<T_TOK / 4, 256, 0, stream>>>(x, rw, rb, topk_idx, topk_w);
    prefix_kernel<<<1, 256, 0, stream>>>(topk_idx, counts, offsets, cursor);
    sg_kernel<<<T_TOK, 256, 0, stream>>>(x, topk_idx, topk_w, offsets, cursor,
                                         Xp, w_of, slot_of);
    cvt_kernel<<<2048, 256, 0, stream>>>(w1, w1b, w2, w2b);

    // fc1: 256x256 tiles over (mt up to 8192 rows, 32 nt of 128 h-cols), two
    // nt-halves for profiler visibility.
    fc1_kernel<<<dim3(32, 16, NE), 512, 0, stream>>>(Xp, w1b, b1, counts, offsets, Hb, 0);
    fc1_kernel<<<dim3(32, 16, NE), 512, 0, stream>>>(Xp, w1b, b1, counts, offsets, Hb, 16);
    // fc2: 256x256 tiles, nt over DIMX/256
    fc2_kernel<<<dim3(32, DIMX / 256, NE), 512, 0, stream>>>(Hb, w2b, b2, counts, offsets, w_of, Os);
    combine_kernel<<<T_TOK, 256, 0, stream>>>(Os, slot_of, out);
}

// Round 4
// 1282.795 us; speedup vs baseline: 1.9648x; 1.9549x over previous
//
#include <hip/hip_runtime.h>

#define T_TOK 8192
#define DIMX 1024
#define HID 4096
#define NE 8
#define TP (T_TOK * 2)   // 16384 routed (token,expert) pairs
#define PADR 128         // pad rows so partial tiles can over-read safely
#define BK 64

typedef unsigned short ushort_t;
typedef __attribute__((ext_vector_type(4))) float f32x4;
typedef __attribute__((ext_vector_type(8))) short bf16x8;
typedef __attribute__((ext_vector_type(8))) unsigned short u16x8;

__device__ __forceinline__ ushort_t f2bf(float f) {
    unsigned u = __float_as_uint(f);
    u += 0x7FFFu + ((u >> 16) & 1u);   // RNE
    return (ushort_t)(u >> 16);
}
__device__ __forceinline__ float b2f(ushort_t h) {
    return __uint_as_float(((unsigned)h) << 16);
}

// async global->LDS, 16B per lane. LDS dest is wave-uniform base + lane*16,
// so lds ptr MUST be base + lane*16 in-order (no padding allowed).
__device__ __forceinline__ void gload_lds16(const void* g, void* l) {
    __builtin_amdgcn_global_load_lds((const __attribute__((address_space(1))) void*)g,
                                     (__attribute__((address_space(3))) void*)l, 16, 0, 0);
}

__device__ __forceinline__ f32x4 mfma16(bf16x8 a, bf16x8 b, f32x4 c) {
    return __builtin_amdgcn_mfma_f32_16x16x32_bf16(a, b, c, 0, 0, 0);
}

// ---------------- routing ----------------

// one wave per token; logits in exact fp32 (no atomics — counts done in prefix)
__global__ __launch_bounds__(256) void router_kernel(
    const float* __restrict__ x, const float* __restrict__ rw, const float* __restrict__ rb,
    int* __restrict__ topk_idx, float* __restrict__ topk_w)
{
    __shared__ float s_rw[NE * DIMX];
    int tid = threadIdx.x;
    for (int i = tid * 4; i < NE * DIMX; i += 1024) {
        float4 v = *(const float4*)(rw + i);
        *(float4*)(s_rw + i) = v;
    }
    __syncthreads();
    int lane = tid & 63, wid = tid >> 6;
    int t = blockIdx.x * 4 + wid;
    const float* xr = x + (size_t)t * DIMX;
    float acc[NE];
#pragma unroll
    for (int e = 0; e < NE; e++) acc[e] = 0.f;
    for (int j = 0; j < DIMX; j += 64) {
        float xv = xr[j + lane];
#pragma unroll
        for (int e = 0; e < NE; e++) acc[e] += xv * s_rw[e * DIMX + j + lane];
    }
#pragma unroll
    for (int e = 0; e < NE; e++) {
#pragma unroll
        for (int off = 32; off > 0; off >>= 1) acc[e] += __shfl_xor(acc[e], off, 64);
    }
    if (lane == 0) {
        float v[NE];
#pragma unroll
        for (int e = 0; e < NE; e++) v[e] = acc[e] + rb[e];
        int i0 = 0; float b0 = v[0];
#pragma unroll
        for (int e = 1; e < NE; e++) if (v[e] > b0) { b0 = v[e]; i0 = e; }  // strict > : lowest idx on tie
        int i1 = -1; float b1v = -1e30f;
#pragma unroll
        for (int e = 0; e < NE; e++) if (e != i0 && v[e] > b1v) { b1v = v[e]; i1 = e; }
        float ex = __expf(b1v - b0);
        float inv = 1.f / (1.f + ex);
        topk_idx[t * 2]     = i0;  topk_idx[t * 2 + 1] = i1;
        topk_w[t * 2]       = inv; topk_w[t * 2 + 1]   = ex * inv;
    }
}

// single block: histogram of topk_idx -> counts, offsets; zero cursor
__global__ __launch_bounds__(256) void prefix_kernel(
    const int* __restrict__ topk_idx, int* __restrict__ counts,
    int* __restrict__ offsets, int* __restrict__ cursor)
{
    __shared__ int hist[NE * 256];
    int tid = threadIdx.x;
    int loc[NE];
#pragma unroll
    for (int e = 0; e < NE; e++) loc[e] = 0;
    for (int i = tid; i < TP; i += 256) loc[topk_idx[i]]++;
#pragma unroll
    for (int e = 0; e < NE; e++) hist[e * 256 + tid] = loc[e];
    __syncthreads();
    if (tid < NE) {
        int s = 0;
        for (int j = 0; j < 256; j++) s += hist[tid * 256 + j];
        counts[tid] = s;
        cursor[tid] = 0;
    }
    __syncthreads();
    if (tid == 0) {
        int s = 0;
        for (int e = 0; e < NE; e++) { offsets[e] = s; s += counts[e]; }
    }
}

// scatter + gather fused: one block per token, copy its row (bf16) to both slots
__global__ __launch_bounds__(256) void sg_kernel(
    const float* __restrict__ x, const int* __restrict__ topk_idx,
    const float* __restrict__ topk_w, const int* __restrict__ offsets,
    int* __restrict__ cursor, ushort_t* __restrict__ Xp,
    float* __restrict__ w_of, int* __restrict__ slot_of)
{
    __shared__ int s_pos[2];
    int t = blockIdx.x;
    if (threadIdx.x == 0) {
        int e0 = topk_idx[2 * t], e1 = topk_idx[2 * t + 1];
        int p0 = offsets[e0] + atomicAdd(&cursor[e0], 1);
        int p1 = offsets[e1] + atomicAdd(&cursor[e1], 1);
        s_pos[0] = p0; s_pos[1] = p1;
        w_of[p0] = topk_w[2 * t]; w_of[p1] = topk_w[2 * t + 1];
        slot_of[2 * t] = p0; slot_of[2 * t + 1] = p1;
    }
    __syncthreads();
    int p0 = s_pos[0], p1 = s_pos[1];
    int i = threadIdx.x;
    float4 v = ((const float4*)(x + (size_t)t * DIMX))[i];
    ushort4 o = make_ushort4(f2bf(v.x), f2bf(v.y), f2bf(v.z), f2bf(v.w));
    ((ushort4*)(Xp + (size_t)p0 * DIMX))[i] = o;
    ((ushort4*)(Xp + (size_t)p1 * DIMX))[i] = o;
}

// ---------------- dtype prep ----------------

// fused fp32->bf16 conversion for w1+w2, grid-stride, 16B stores
__global__ __launch_bounds__(256) void cvt_kernel(
    const float* __restrict__ w1, ushort_t* __restrict__ w1d,
    const float* __restrict__ w2, ushort_t* __restrict__ w2d)
{
    const int n8_w1 = NE * 2 * HID * DIMX / 8;
    const int n8_tot = n8_w1 + NE * DIMX * HID / 8;
    int stride = gridDim.x * 256;
    for (int i = blockIdx.x * 256 + threadIdx.x; i < n8_tot; i += stride) {
        const float* src; ushort_t* dst; int j;
        if (i < n8_w1) { src = w1; dst = w1d; j = i; }
        else           { src = w2; dst = w2d; j = i - n8_w1; }
        float4 a = ((const float4*)src)[j * 2];
        float4 b = ((const float4*)src)[j * 2 + 1];
        u16x8 o = { f2bf(a.x), f2bf(a.y), f2bf(a.z), f2bf(a.w),
                    f2bf(b.x), f2bf(b.y), f2bf(b.z), f2bf(b.w) };
        ((u16x8*)dst)[j] = o;
    }
}

// ---------------- fc1: H = silu(Xp W1a^T + b1a) * (Xp W1b^T + b1b) ----------------
// block: 128 rows x 64 hidden cols (both swiglu halves). 4 waves 2x2.
// XCD-affinity swizzle: e = wg&7 pins each expert to one XCD's L2 (wgid%8
// round-robin heuristic). Within an expert: mt-bands of 8 tiles (2 MB of A)
// held hot across all 64 nt B-panels (nt-outer, mt-inner) -> A fetched ~once
// per band instead of once per nt.
__global__ __launch_bounds__(256, 2) void fc1_kernel(
    const ushort_t* __restrict__ Xp, const ushort_t* __restrict__ w1b,
    const float* __restrict__ b1,
    const int* __restrict__ counts, const int* __restrict__ offsets,
    ushort_t* __restrict__ H)
{
    // swizzled decode: wg -> (e, band, nt, mi)
    const int wg = blockIdx.x;
    const int e  = wg & 7;
    const int r  = wg >> 3;           // [0, 2048) per expert
    const int band = r >> 9;          // [0,4): mt-band of 8 tiles
    const int rem  = r & 511;
    const int nt   = rem >> 3;        // [0,64) nt outer
    const int mt   = band * 8 + (rem & 7);   // mt inner (band-local)

    const int cnt = counts[e];
    if (mt * 128 >= cnt) return;
    const int base = offsets[e] + mt * 128;
    int rows_valid = cnt - mt * 128; if (rows_valid > 128) rows_valid = 128;

    __shared__ ushort_t As[128 * BK];    // 16 KB
    __shared__ ushort_t Bs1[64 * BK];    //  8 KB
    __shared__ ushort_t Bs2[64 * BK];    //  8 KB

    const int tid = threadIdx.x, lane = tid & 63, wid = tid >> 6;
    const int wave_m = wid >> 1, wave_n = wid & 1;

    const ushort_t* Ag  = Xp + (size_t)base * DIMX;
    const ushort_t* B1g = w1b + ((size_t)e * 2 * HID + (size_t)nt * 64) * DIMX;
    const ushort_t* B2g = B1g + (size_t)HID * DIMX;

    // staging: XOR-swizzle chunk c' = c ^ (row&7) so frag ds_read_b128 is ~2-way (free)
    const ushort_t* agp[4]; ushort_t* alp[4];
#pragma unroll
    for (int i = 0; i < 4; i++) {
        int s = wid * 4 + i;
        int r2 = s * 8 + (lane >> 3);
        int c = (lane & 7) ^ (r2 & 7);
        agp[i] = Ag + (size_t)r2 * DIMX + c * 8;
        alp[i] = As + s * 512 + lane * 8;
    }
    const ushort_t* bgp[4]; ushort_t* blp[4];
#pragma unroll
    for (int i = 0; i < 2; i++) {
        int s = wid * 2 + i;
        int r2 = s * 8 + (lane >> 3);
        int c = (lane & 7) ^ (r2 & 7);
        bgp[i]     = B1g + (size_t)r2 * DIMX + c * 8;
        blp[i]     = Bs1 + s * 512 + lane * 8;
        bgp[2 + i] = B2g + (size_t)r2 * DIMX + c * 8;
        blp[2 + i] = Bs2 + s * 512 + lane * 8;
    }

    f32x4 acc1[4][2], acc2[4][2];
#pragma unroll
    for (int mf = 0; mf < 4; mf++)
#pragma unroll
        for (int nf = 0; nf < 2; nf++) {
            acc1[mf][nf] = (f32x4){0.f, 0.f, 0.f, 0.f};
            acc2[mf][nf] = (f32x4){0.f, 0.f, 0.f, 0.f};
        }

    const int q = lane >> 4, rA = lane & 15;
    for (int ko = 0; ko < DIMX / BK; ko++) {
#pragma unroll
        for (int i = 0; i < 4; i++) gload_lds16(agp[i], alp[i]);
#pragma unroll
        for (int i = 0; i < 4; i++) gload_lds16(bgp[i], blp[i]);
#pragma unroll
        for (int i = 0; i < 4; i++) { agp[i] += BK; bgp[i] += BK; }
        __syncthreads();

        bf16x8 af[4][2], bf1[2][2], bf2[2][2];
#pragma unroll
        for (int mf = 0; mf < 4; mf++) {
            int r2 = wave_m * 64 + mf * 16 + rA;
            const ushort_t* rp = As + r2 * BK;
            af[mf][0] = *(const bf16x8*)(rp + ((q    ) ^ (r2 & 7)) * 8);
            af[mf][1] = *(const bf16x8*)(rp + ((q + 4) ^ (r2 & 7)) * 8);
        }
#pragma unroll
        for (int nf = 0; nf < 2; nf++) {
            int r2 = wave_n * 32 + nf * 16 + rA;
            const ushort_t* rp1 = Bs1 + r2 * BK;
            const ushort_t* rp2 = Bs2 + r2 * BK;
            bf1[nf][0] = *(const bf16x8*)(rp1 + ((q    ) ^ (r2 & 7)) * 8);
            bf1[nf][1] = *(const bf16x8*)(rp1 + ((q + 4) ^ (r2 & 7)) * 8);
            bf2[nf][0] = *(const bf16x8*)(rp2 + ((q    ) ^ (r2 & 7)) * 8);
            bf2[nf][1] = *(const bf16x8*)(rp2 + ((q + 4) ^ (r2 & 7)) * 8);
        }
#pragma unroll
        for (int mf = 0; mf < 4; mf++)
#pragma unroll
            for (int nf = 0; nf < 2; nf++) {
                acc1[mf][nf] = mfma16(af[mf][0], bf1[nf][0], acc1[mf][nf]);
                acc1[mf][nf] = mfma16(af[mf][1], bf1[nf][1], acc1[mf][nf]);
                acc2[mf][nf] = mfma16(af[mf][0], bf2[nf][0], acc2[mf][nf]);
                acc2[mf][nf] = mfma16(af[mf][1], bf2[nf][1], acc2[mf][nf]);
            }
        __syncthreads();
    }

    // epilogue: C/D layout col=lane&15, row=(lane>>4)*4+reg
    const float* b1p = b1 + (size_t)e * 2 * HID + (size_t)nt * 64;
    const bool full = (rows_valid == 128);
#pragma unroll
    for (int mf = 0; mf < 4; mf++) {
#pragma unroll
        for (int nf = 0; nf < 2; nf++) {
            int col = wave_n * 32 + nf * 16 + rA;
            float bb1 = b1p[col];
            float bb2 = b1p[HID + col];
#pragma unroll
            for (int rr = 0; rr < 4; rr++) {
                int row = wave_m * 64 + mf * 16 + q * 4 + rr;
                if (full || row < rows_valid) {
                    float v1 = acc1[mf][nf][rr] + bb1;
                    float v2 = acc2[mf][nf][rr] + bb2;
                    float hv = v1 * v2 / (1.f + __expf(-v1));   // silu(v1)*v2
                    H[(size_t)(base + row) * HID + (size_t)nt * 64 + col] = f2bf(hv);
                }
            }
        }
    }
}

// ---------------- fc2: Os[pos] = w_of[pos] * (H[pos] W2^T + b2) ----------------
// block: 128 rows x 128 out cols. 4 waves 2x2. Expert->XCD affinity via wg&7;
// within expert: nt outer, mt fastest (A-sharers 32 apart -> same-L2 temporal
// reuse window; B panel hot across the mt sweep).
__global__ __launch_bounds__(256, 2) void fc2_kernel(
    const ushort_t* __restrict__ H, const ushort_t* __restrict__ w2b,
    const float* __restrict__ b2,
    const int* __restrict__ counts, const int* __restrict__ offsets,
    const float* __restrict__ w_of, ushort_t* __restrict__ Os)
{
    const int wg = blockIdx.x;
    const int e  = wg & 7;
    const int r  = wg >> 3;          // [0,256) per expert
    const int nt = r >> 5;           // [0,8) nt outer
    const int mt = r & 31;           // mt fastest

    const int cnt = counts[e];
    if (mt * 128 >= cnt) return;
    const int base = offsets[e] + mt * 128;
    int rows_valid = cnt - mt * 128; if (rows_valid > 128) rows_valid = 128;

    __shared__ ushort_t As[128 * BK];   // 16 KB
    __shared__ ushort_t Bs[128 * BK];   // 16 KB

    const int tid = threadIdx.x, lane = tid & 63, wid = tid >> 6;
    const int wave_m = wid >> 1, wave_n = wid & 1;

    const ushort_t* Ag = H + (size_t)base * HID;
    const ushort_t* Bg = w2b + ((size_t)e * DIMX + (size_t)nt * 128) * HID;

    const ushort_t* agp[4]; ushort_t* alp[4];
    const ushort_t* bgp[4]; ushort_t* blp[4];
#pragma unroll
    for (int i = 0; i < 4; i++) {
        int s = wid * 4 + i;
        int r2 = s * 8 + (lane >> 3);
        int c = (lane & 7) ^ (r2 & 7);
        agp[i] = Ag + (size_t)r2 * HID + c * 8;
        alp[i] = As + s * 512 + lane * 8;
        bgp[i] = Bg + (size_t)r2 * HID + c * 8;
        blp[i] = Bs + s * 512 + lane * 8;
    }

    f32x4 acc[4][4];
#pragma unroll
    for (int mf = 0; mf < 4; mf++)
#pragma unroll
        for (int nf = 0; nf < 4; nf++) acc[mf][nf] = (f32x4){0.f, 0.f, 0.f, 0.f};

    const int q = lane >> 4, rA = lane & 15;
    for (int ko = 0; ko < HID / BK; ko++) {
#pragma unroll
        for (int i = 0; i < 4; i++) gload_lds16(agp[i], alp[i]);
#pragma unroll
        for (int i = 0; i < 4; i++) gload_lds16(bgp[i], blp[i]);
#pragma unroll
        for (int i = 0; i < 4; i++) { agp[i] += BK; bgp[i] += BK; }
        __syncthreads();

        bf16x8 af[4][2], bfr[4][2];
#pragma unroll
        for (int mf = 0; mf < 4; mf++) {
            int r2 = wave_m * 64 + mf * 16 + rA;
            const ushort_t* rp = As + r2 * BK;
            af[mf][0] = *(const bf16x8*)(rp + ((q    ) ^ (r2 & 7)) * 8);
            af[mf][1] = *(const bf16x8*)(rp + ((q + 4) ^ (r2 & 7)) * 8);
        }
#pragma unroll
        for (int nf = 0; nf < 4; nf++) {
            int r2 = wave_n * 64 + nf * 16 + rA;
            const ushort_t* rp = Bs + r2 * BK;
            bfr[nf][0] = *(const bf16x8*)(rp + ((q    ) ^ (r2 & 7)) * 8);
            bfr[nf][1] = *(const bf16x8*)(rp + ((q + 4) ^ (r2 & 7)) * 8);
        }
#pragma unroll
        for (int mf = 0; mf < 4; mf++)
#pragma unroll
            for (int nf = 0; nf < 4; nf++) {
                acc[mf][nf] = mfma16(af[mf][0], bfr[nf][0], acc[mf][nf]);
                acc[mf][nf] = mfma16(af[mf][1], bfr[nf][1], acc[mf][nf]);
            }
        __syncthreads();
    }

    const float* b2p = b2 + (size_t)e * DIMX + (size_t)nt * 128;
    const bool full = (rows_valid == 128);
#pragma unroll
    for (int mf = 0; mf < 4; mf++) {
#pragma unroll
        for (int rr = 0; rr < 4; rr++) {
            int row = wave_m * 64 + mf * 16 + q * 4 + rr;
            if (full || row < rows_valid) {
                float wv = w_of[base + row];
#pragma unroll
                for (int nf = 0; nf < 4; nf++) {
                    int col = wave_n * 64 + nf * 16 + rA;
                    float val = (acc[mf][nf][rr] + b2p[col]) * wv;
                    Os[(size_t)(base + row) * DIMX + (size_t)nt * 128 + col] = f2bf(val);
                }
            }
        }
    }
}

// ---------------- combine: out[t] = Os[slot0] + Os[slot1] (already weighted) ----------------
__global__ __launch_bounds__(256) void combine_kernel(
    const ushort_t* __restrict__ Os, const int* __restrict__ slot_of, float* __restrict__ out)
{
    int t = blockIdx.x;
    int p0 = slot_of[t * 2], p1 = slot_of[t * 2 + 1];
    int i = threadIdx.x;
    ushort4 a = ((const ushort4*)(Os + (size_t)p0 * DIMX))[i];
    ushort4 b = ((const ushort4*)(Os + (size_t)p1 * DIMX))[i];
    float4 o;
    o.x = b2f(a.x) + b2f(b.x);
    o.y = b2f(a.y) + b2f(b.y);
    o.z = b2f(a.z) + b2f(b.z);
    o.w = b2f(a.w) + b2f(b.w);
    ((float4*)(out + (size_t)t * DIMX))[i] = o;
}

// ---------------- launch ----------------

extern "C" void kernel_launch(void* const* d_in, const int* in_sizes, int n_in,
                              void* d_out, int out_size, void* d_ws, size_t ws_size,
                              hipStream_t stream) {
    (void)in_sizes; (void)n_in; (void)out_size; (void)ws_size;
    const float* x  = (const float*)d_in[0];
    const float* rw = (const float*)d_in[1];
    const float* rb = (const float*)d_in[2];
    const float* w1 = (const float*)d_in[3];
    const float* b1 = (const float*)d_in[4];
    const float* w2 = (const float*)d_in[5];
    const float* b2 = (const float*)d_in[6];
    float* out = (float*)d_out;

    // workspace layout (~357 MB). Os overlays Xp (dead after fc1).
    char* p = (char*)d_ws;
    ushort_t* w1b = (ushort_t*)p; p += (size_t)NE * 2 * HID * DIMX * 2;        // 128 MB
    ushort_t* w2b = (ushort_t*)p; p += (size_t)NE * DIMX * HID * 2;            //  64 MB
    ushort_t* Xp  = (ushort_t*)p; p += (size_t)(TP + PADR) * DIMX * 2;         //  33 MB
    ushort_t* Hb  = (ushort_t*)p; p += (size_t)(TP + PADR) * HID * 2;          // 132 MB
    int* ints     = (int*)p;      p += 24 * sizeof(int);
    int*   counts  = ints;
    int*   cursor  = ints + 8;
    int*   offsets = ints + 16;
    int*   topk_idx = (int*)p;   p += (size_t)TP * 4;
    float* topk_w   = (float*)p; p += (size_t)TP * 4;
    float* w_of     = (float*)p; p += (size_t)TP * 4;
    int*   slot_of  = (int*)p;   p += (size_t)TP * 4;
    ushort_t* Os = Xp;                  // 32 MB needed, 33 MB available

    router_kernel<<<T_TOK / 4, 256, 0, stream>>>(x, rw, rb, topk_idx, topk_w);
    prefix_kernel<<<1, 256, 0, stream>>>(topk_idx, counts, offsets, cursor);
    sg_kernel<<<T_TOK, 256, 0, stream>>>(x, topk_idx, topk_w, offsets, cursor,
                                         Xp, w_of, slot_of);
    cvt_kernel<<<2048, 256, 0, stream>>>(w1, w1b, w2, w2b);

    // fc1: merged single launch, 1-D swizzled grid: 8 e x 4 band x 64 nt x 8 mi
    fc1_kernel<<<NE * 32 * 64, 256, 0, stream>>>(Xp, w1b, b1, counts, offsets, Hb);
    // fc2: 1-D swizzled grid: 8 e x 8 nt x 32 mt
    fc2_kernel<<<NE * 8 * 32, 256, 0, stream>>>(Hb, w2b, b2, counts, offsets, w_of, Os);
    combine_kernel<<<T_TOK, 256, 0, stream>>>(Os, slot_of, out);
}